// Round 1
// baseline (233.776 us; speedup 1.0000x reference)
//
#include <hip/hip_runtime.h>

typedef int   int4v   __attribute__((ext_vector_type(4)));
typedef float float4v __attribute__((ext_vector_type(4)));

#define T_TOK 16384
#define HD    1024
#define IE    256
#define EN    8
#define VSZ   100000

// meta[] int indices
#define M_OFF 16   // [9] group offsets
#define M_TS1 25   // [9] gemm tile-start prefix (Mtile=64)

// ws byte offsets (all 16-aligned) — same layout slots as previous version
#define XQ_OFF   0ull           // T*1024 int8 (token-ordered now)
#define PB1_OFF  21053440ull    // 8*64*512*16 int8 (gate|up packed)
#define PB2_OFF  25247744ull    // 8*16*1024*16 int8 (down packed)
#define PERM_OFF 27344896ull    // T int32
#define XS_OFF   27410688ull    // T float (token-ordered now)
#define META_OFF 27542272ull    // 64 int32

// async global->LDS, 16B per lane; LDS dest = wave-uniform base + lane*16
__device__ __forceinline__ void gload16(const void* g, void* l) {
    __builtin_amdgcn_global_load_lds(
        (const __attribute__((address_space(1))) unsigned int*)g,
        (__attribute__((address_space(3))) unsigned int*)l,
        16, 0, 0);
}

// ---------------------------------------------------------------------------
// Routing: hist + scan + assign + meta, one block of 1024 threads.
// Each thread owns 16 consecutive tokens; per-thread counts live in LDS,
// scanned wave-wise by shuffles, then across 16 waves, then across experts.
// ---------------------------------------------------------------------------
__global__ __launch_bounds__(1024) void k_route(const int* __restrict__ ids,
                                                const int* __restrict__ t2e,
                                                int* __restrict__ perm,
                                                int* __restrict__ meta) {
    __shared__ int lbase[1024][EN];   // counts -> intra-wave exclusive base/cursor
    __shared__ int wsum[16][EN];      // wave totals -> wave-exclusive base
    __shared__ int goff[EN], tot[EN];
    const int tid = threadIdx.x, lane = tid & 63, wv = tid >> 6;

    #pragma unroll
    for (int e = 0; e < EN; ++e) lbase[tid][e] = 0;
    int e_of[16];
    #pragma unroll
    for (int i = 0; i < 16; ++i) {
        int id = ids[tid * 16 + i];
        id = min(max(id, 0), VSZ - 1);
        int e = t2e[id];
        e_of[i] = e;
        lbase[tid][e]++;
    }
    // per-expert inclusive wave scan
    #pragma unroll
    for (int e = 0; e < EN; ++e) {
        int v = lbase[tid][e];
        int inc = v;
        #pragma unroll
        for (int s = 1; s < 64; s <<= 1) {
            int u = __shfl_up(inc, s, 64);
            if (lane >= s) inc += u;
        }
        lbase[tid][e] = inc - v;          // thread-exclusive within wave
        if (lane == 63) wsum[wv][e] = inc; // wave total
    }
    __syncthreads();
    if (tid < EN) {                        // exclusive scan of 16 wave totals
        int run = 0;
        for (int w2 = 0; w2 < 16; ++w2) { int t = wsum[w2][tid]; wsum[w2][tid] = run; run += t; }
        tot[tid] = run;
    }
    __syncthreads();
    if (tid == 0) {
        int off = 0, t1 = 0;
        meta[M_OFF] = 0; meta[M_TS1] = 0;
        #pragma unroll
        for (int e = 0; e < EN; ++e) {
            goff[e] = off;
            off += tot[e];
            t1 += (tot[e] + 63) >> 6;
            meta[M_OFF + e + 1] = off;
            meta[M_TS1 + e + 1] = t1;
        }
    }
    __syncthreads();
    #pragma unroll
    for (int i = 0; i < 16; ++i) {
        int e = e_of[i];
        int c = lbase[tid][e];
        lbase[tid][e] = c + 1;
        perm[goff[e] + wsum[wv][e] + c] = tid * 16 + i;
    }
}

// ---------------------------------------------------------------------------
// k_pre: token-ordered activation quantization (blocks 0..4095, wave per token)
//        + weight repack into MFMA fragment layout (blocks 4096..5631).
// Fragment layout: elem(k,n) at ((k>>4)*N + n)*16 + (k&15)
// ---------------------------------------------------------------------------
__global__ __launch_bounds__(256) void k_pre(const float* __restrict__ hidden,
                                             const int* __restrict__ gq,
                                             const int* __restrict__ uq,
                                             const int* __restrict__ dq,
                                             signed char* __restrict__ xq,
                                             float* __restrict__ xs,
                                             signed char* __restrict__ pb1,
                                             signed char* __restrict__ pb2) {
    int b = blockIdx.x;
    if (b < 4096) {
        int w = threadIdx.x >> 6, lane = threadIdx.x & 63;
        int token = (b << 2) + w;
        const float* row = hidden + (size_t)token * HD;
        float v[16];
        #pragma unroll
        for (int j = 0; j < 4; ++j) {
            float4v f = *(const float4v*)(row + lane * 16 + j * 4);
            v[j*4+0] = f[0]; v[j*4+1] = f[1]; v[j*4+2] = f[2]; v[j*4+3] = f[3];
        }
        float mx = 0.0f;
        #pragma unroll
        for (int j = 0; j < 16; ++j) mx = fmaxf(mx, fabsf(v[j]));
        #pragma unroll
        for (int s = 1; s < 64; s <<= 1) mx = fmaxf(mx, __shfl_xor(mx, s, 64));
        float sc = fmaxf(mx / 127.0f, 1e-8f);
        if (lane == 0) xs[token] = sc;
        int4v pk;
        #pragma unroll
        for (int j = 0; j < 4; ++j) {
            int bb[4];
            #pragma unroll
            for (int u = 0; u < 4; ++u) {
                float t = rintf(v[j*4+u] / sc);           // round-half-even == jnp.round
                t = fminf(fmaxf(t, -128.0f), 127.0f);
                bb[u] = (int)t;
            }
            pk[j] = (bb[0] & 255) | ((bb[1] & 255) << 8) | ((bb[2] & 255) << 16) | (bb[3] << 24);
        }
        *(int4v*)(xq + (size_t)token * HD + lane * 16) = pk;
    } else {
        int idx = (b - 4096) * 256 + threadIdx.x;   // 0 .. 393215
        if (idx < 262144) {                          // gate|up fragments [8][64][512]
            int n = idx & 511, kc = (idx >> 9) & 63, e = idx >> 15;
            const int* src = (n < 256) ? gq + (((size_t)((e << 10) + (kc << 4)) << 8) + n)
                                       : uq + (((size_t)((e << 10) + (kc << 4)) << 8) + (n - 256));
            int4v pk;
            #pragma unroll
            for (int jj = 0; jj < 4; ++jj) {
                int b0 = src[(size_t)(jj * 4 + 0) << 8], b1 = src[(size_t)(jj * 4 + 1) << 8];
                int b2 = src[(size_t)(jj * 4 + 2) << 8], b3 = src[(size_t)(jj * 4 + 3) << 8];
                pk[jj] = (b0 & 255) | ((b1 & 255) << 8) | ((b2 & 255) << 16) | (b3 << 24);
            }
            *(int4v*)(pb1 + ((size_t)((((e << 6) + kc) << 9) + n) << 4)) = pk;
        } else {                                     // down fragments [8][16][1024]
            int j = idx - 262144;
            int n = j & 1023, kc = (j >> 10) & 15, e = j >> 14;
            const int* src = dq + (((size_t)((e << 8) + (kc << 4)) << 10) + n);
            int4v pk;
            #pragma unroll
            for (int jj = 0; jj < 4; ++jj) {
                int b0 = src[(size_t)(jj * 4 + 0) << 10], b1 = src[(size_t)(jj * 4 + 1) << 10];
                int b2 = src[(size_t)(jj * 4 + 2) << 10], b3 = src[(size_t)(jj * 4 + 3) << 10];
                pk[jj] = (b0 & 255) | ((b1 & 255) << 8) | ((b2 & 255) << 16) | (b3 << 24);
            }
            *(int4v*)(pb2 + ((size_t)((((e << 4) + kc) << 10) + n) << 4)) = pk;
        }
    }
}

// ---------------------------------------------------------------------------
// k_mlp: fused GEMM1 (64x512xK1024, gate|up) -> silu*up -> rowwise requant in
// LDS -> GEMM2 (64x1024xK256, down) -> scattered out write.
// LDS budget: lB 2x32KB + 16KB arena = 81920B exactly -> 2 blocks/CU.
// arena phase 1: [lA dbuf 8K][pmax 1K][rsc 256B][ptok 256B]; epilogue re-uses
// the whole arena as the swizzled 64x256 int8 iq tile for phase 2.
// ---------------------------------------------------------------------------
__global__ __launch_bounds__(256, 2) void k_mlp(const signed char* __restrict__ xq,
                                                const signed char* __restrict__ pb1,
                                                const signed char* __restrict__ pb2,
                                                const float* __restrict__ xs,
                                                const float* __restrict__ gsc,
                                                const float* __restrict__ usc,
                                                const float* __restrict__ dsc,
                                                const int* __restrict__ meta,
                                                const int* __restrict__ perm,
                                                float* __restrict__ out) {
    int b = blockIdx.x;
    int e = -1, m0 = 0, gend = 0;
    #pragma unroll
    for (int i = 0; i < EN; ++i) {
        int s0 = meta[M_TS1 + i], s1 = meta[M_TS1 + i + 1];
        if (b >= s0 && b < s1) { e = i; m0 = meta[M_OFF + i] + ((b - s0) << 6); gend = meta[M_OFF + i + 1]; }
    }
    if (e < 0) return;
    const int w = threadIdx.x >> 6, lane = threadIdx.x & 63;
    const int q = lane >> 4, r = lane & 15;

    __shared__ __align__(16) signed char lB[2][32768];
    __shared__ __align__(16) signed char arena[16384];
    float* pmax = (float*)(arena + 8192);   // [4][64]
    float* rsc  = (float*)(arena + 9216);   // [64]
    int*   ptok = (int*)(arena + 9472);     // [64]

    if (threadIdx.x < 64) ptok[threadIdx.x] = perm[min(m0 + (int)threadIdx.x, T_TOK - 1)];
    __syncthreads();

    int tokr[4][4];
    #pragma unroll
    for (int mi = 0; mi < 4; ++mi)
        #pragma unroll
        for (int g = 0; g < 4; ++g)
            tokr[mi][g] = ptok[(mi << 4) + (q << 2) + g];

    const signed char* pbe1 = pb1 + (size_t)e * (64 * 512 * 16);
    const signed char* pbe2 = pb2 + (size_t)e * (16 * 1024 * 16);
    const int arow = (w << 4) + (lane >> 2);          // staging row 0..63
    const int acq  = (lane & 3) ^ ((lane >> 2) & 3);  // swizzled q-slot content
    const signed char* ga_base = xq + (size_t)ptok[arow] * HD + (acq << 4);

    #define G1_STAGE(buf, kt)                                                          \
        {                                                                              \
            int kc0 = (kt) << 2;                                                       \
            _Pragma("unroll")                                                          \
            for (int j = 0; j < 8; ++j) {                                              \
                int n = ((j << 6) + lane) ^ ((w & 1) << 3);                            \
                gload16(pbe1 + (((size_t)(kc0 + w) * 512 + n) << 4),                   \
                        &lB[buf][((w << 3) + j) << 10]);                               \
            }                                                                          \
            gload16(ga_base + ((kt) << 6), arena + ((buf) << 12) + (w << 10));         \
        }

    #define G2_STAGE(buf, st)                                                          \
        {                                                                              \
            int kc0 = ((st) & 3) << 2; int nhs = (st) >> 2;                            \
            _Pragma("unroll")                                                          \
            for (int j = 0; j < 8; ++j) {                                              \
                int n = ((j << 6) + lane) ^ ((w & 1) << 3);                            \
                gload16(pbe2 + (((size_t)(kc0 + w) * 1024 + (nhs << 9) + n) << 4),     \
                        &lB[buf][((w << 3) + j) << 10]);                               \
            }                                                                          \
        }

    int4v zero = {0, 0, 0, 0};
    int4v accg[4][4], accu[4][4];
    #pragma unroll
    for (int mi = 0; mi < 4; ++mi)
        #pragma unroll
        for (int i = 0; i < 4; ++i) { accg[mi][i] = zero; accu[mi][i] = zero; }

    // ---------------- phase 1: gate|up GEMM ----------------
    G1_STAGE(0, 0);
    for (int kt = 0; kt < 16; ++kt) {
        int cur = kt & 1;
        if (kt < 15) G1_STAGE(cur ^ 1, kt + 1);
        __syncthreads();
        int4v a[4];
        #pragma unroll
        for (int mi = 0; mi < 4; ++mi)
            a[mi] = *(const int4v*)&arena[(cur << 12) + ((((mi << 4) + r) << 6) + ((q ^ (r & 3)) << 4))];
        #pragma unroll
        for (int i = 0; i < 4; ++i) {
            int n = (w << 6) + (i << 4) + r;
            int sg = (q << 9) + (n ^ ((q & 1) << 3));
            int su = (q << 9) + ((n + 256) ^ ((q & 1) << 3));
            int4v bg = *(const int4v*)&lB[cur][sg << 4];
            int4v bu = *(const int4v*)&lB[cur][su << 4];
            #pragma unroll
            for (int mi = 0; mi < 4; ++mi) {
                accg[mi][i] = __builtin_amdgcn_mfma_i32_16x16x64_i8(a[mi], bg, accg[mi][i], 0, 0, 0);
                accu[mi][i] = __builtin_amdgcn_mfma_i32_16x16x64_i8(a[mi], bu, accu[mi][i], 0, 0, 0);
            }
        }
        __syncthreads();
    }
    #undef G1_STAGE

    // prefetch first down-weight tile; HBM latency hides under the epilogue
    G2_STAGE(0, 0);

    // ---------------- epilogue: silu*up, row max, requant ----------------
    float gs[4], us[4];
    #pragma unroll
    for (int i = 0; i < 4; ++i) {
        int n = (w << 6) + (i << 4) + r;
        gs[i] = gsc[e * IE + n];
        us[i] = usc[e * IE + n];
    }
    float xsr[4][4];
    #pragma unroll
    for (int mi = 0; mi < 4; ++mi)
        #pragma unroll
        for (int g = 0; g < 4; ++g)
            xsr[mi][g] = xs[tokr[mi][g]];

    float inter[4][4][4];
    float pm[4][4];
    #pragma unroll
    for (int mi = 0; mi < 4; ++mi)
        #pragma unroll
        for (int g = 0; g < 4; ++g) {
            float mx = 0.0f;
            #pragma unroll
            for (int i = 0; i < 4; ++i) {
                float gv = (float)accg[mi][i][g] * xsr[mi][g] * gs[i];
                float uv = (float)accu[mi][i][g] * xsr[mi][g] * us[i];
                float sg = gv / (1.0f + expf(-gv));
                float vv = sg * uv;
                inter[mi][i][g] = vv;
                mx = fmaxf(mx, fabsf(vv));
            }
            #pragma unroll
            for (int s = 1; s < 16; s <<= 1) mx = fmaxf(mx, __shfl_xor(mx, s, 64));
            pm[mi][g] = mx;
        }

    if (r == 0) {
        #pragma unroll
        for (int mi = 0; mi < 4; ++mi)
            #pragma unroll
            for (int g = 0; g < 4; ++g)
                pmax[(w << 6) + (mi << 4) + (q << 2) + g] = pm[mi][g];
    }
    __syncthreads();
    if (threadIdx.x < 64) {
        int row = threadIdx.x;
        float mx = fmaxf(fmaxf(pmax[row], pmax[64 + row]), fmaxf(pmax[128 + row], pmax[192 + row]));
        rsc[row] = fmaxf(mx / 127.0f, 1e-8f);
    }
    __syncthreads();
    float rscr[4][4];
    #pragma unroll
    for (int mi = 0; mi < 4; ++mi)
        #pragma unroll
        for (int g = 0; g < 4; ++g)
            rscr[mi][g] = rsc[(mi << 4) + (q << 2) + g];
    __syncthreads();   // everyone done reading arena metadata before iq overlay

    // phase 2: quantize inter -> swizzled LDS iq tile (overlays whole arena)
    // slot16(row, c) = c ^ (row & 3); byte = col & 15
    #pragma unroll
    for (int mi = 0; mi < 4; ++mi)
        #pragma unroll
        for (int g = 0; g < 4; ++g) {
            int row = (mi << 4) + (q << 2) + g;
            float sc = rscr[mi][g];
            #pragma unroll
            for (int i = 0; i < 4; ++i) {
                float t = rintf(inter[mi][i][g] / sc);
                t = fminf(fmaxf(t, -128.0f), 127.0f);
                arena[(row << 8) + ((((w << 2) + i) ^ (row & 3)) << 4) + r] = (signed char)(int)t;
            }
        }

    // ---------------- phase 3: down GEMM, N in 2 halves ----------------
    int4v acc2[4][8];
    for (int st = 0; st < 8; ++st) {     // st = nh*4 + kt2
        int cur = st & 1;
        if (st < 7) G2_STAGE(cur ^ 1, st + 1);
        if ((st & 3) == 0) {
            #pragma unroll
            for (int mi = 0; mi < 4; ++mi)
                #pragma unroll
                for (int i = 0; i < 8; ++i) acc2[mi][i] = zero;
        }
        __syncthreads();                 // iq tile + lB[cur] ready
        int4v a2[4];
        #pragma unroll
        for (int mi = 0; mi < 4; ++mi) {
            int row2 = (mi << 4) + r;
            a2[mi] = *(const int4v*)&arena[(row2 << 8) + (((((st & 3) << 2) + q) ^ (r & 3)) << 4)];
        }
        #pragma unroll
        for (int i = 0; i < 8; ++i) {
            int n = (w << 7) + (i << 4) + r;
            int sb = (q << 9) + (n ^ ((q & 1) << 3));
            int4v bb = *(const int4v*)&lB[cur][sb << 4];
            #pragma unroll
            for (int mi = 0; mi < 4; ++mi)
                acc2[mi][i] = __builtin_amdgcn_mfma_i32_16x16x64_i8(a2[mi], bb, acc2[mi][i], 0, 0, 0);
        }
        if ((st & 3) == 3) {
            int nhs = st >> 2;
            float ds[8];
            #pragma unroll
            for (int i = 0; i < 8; ++i)
                ds[i] = dsc[e * HD + (nhs << 9) + (w << 7) + (i << 4) + r];
            #pragma unroll
            for (int mi = 0; mi < 4; ++mi)
                #pragma unroll
                for (int g = 0; g < 4; ++g) {
                    int slot = m0 + (mi << 4) + (q << 2) + g;
                    if (slot < gend) {
                        size_t ob = (size_t)tokr[mi][g] * HD + (nhs << 9) + (w << 7) + r;
                        #pragma unroll
                        for (int i = 0; i < 8; ++i)
                            out[ob + (i << 4)] = (float)acc2[mi][i][g] * rscr[mi][g] * ds[i];
                    }
                }
        }
        __syncthreads();
    }
    #undef G2_STAGE
}

extern "C" void kernel_launch(void* const* d_in, const int* in_sizes, int n_in,
                              void* d_out, int out_size, void* d_ws, size_t ws_size,
                              hipStream_t stream) {
    const float* hidden = (const float*)d_in[0];
    const int*   ids    = (const int*)d_in[1];
    const int*   gq     = (const int*)d_in[2];
    const float* gsc    = (const float*)d_in[3];
    const int*   uq     = (const int*)d_in[4];
    const float* usc    = (const float*)d_in[5];
    const int*   dq     = (const int*)d_in[6];
    const float* dsc    = (const float*)d_in[7];
    const int*   t2e    = (const int*)d_in[8];
    float* out = (float*)d_out;

    char* ws = (char*)d_ws;
    signed char* xq  = (signed char*)(ws + XQ_OFF);
    signed char* pb1 = (signed char*)(ws + PB1_OFF);
    signed char* pb2 = (signed char*)(ws + PB2_OFF);
    int*   perm = (int*)(ws + PERM_OFF);
    float* xs   = (float*)(ws + XS_OFF);
    int*   meta = (int*)(ws + META_OFF);

    k_route<<<1, 1024, 0, stream>>>(ids, t2e, perm, meta);
    k_pre<<<5632, 256, 0, stream>>>(hidden, gq, uq, dq, xq, xs, pb1, pb2);
    k_mlp<<<264, 256, 0, stream>>>(xq, pb1, pb2, xs, gsc, usc, dsc, meta, perm, out);
}

// Round 2
// 204.589 us; speedup vs baseline: 1.1427x; 1.1427x over previous
//
#include <hip/hip_runtime.h>

typedef int   int4v   __attribute__((ext_vector_type(4)));
typedef float float4v __attribute__((ext_vector_type(4)));

#define T_TOK 16384
#define HD    1024
#define IE    256
#define EN    8
#define VSZ   100000

// meta[] int indices
#define M_OFF 16   // [9] group offsets
#define M_TS1 25   // [9] gemm tile-start prefix (Mtile=32)

// ws byte offsets (all 16-aligned)
#define XQ_OFF   0ull           // T*1024 int8 (token-ordered)
#define PB1_OFF  21053440ull    // 8*64*512*16 int8 (gate|up packed)
#define PB2_OFF  25247744ull    // 8*16*1024*16 int8 (down packed)
#define PERM_OFF 27344896ull    // T int32
#define XS_OFF   27410688ull    // T float (token-ordered)
#define META_OFF 27542272ull    // 64 int32
#define BC_OFF   27542528ull    // 64*8 int32 per-block histograms
#define BB_OFF   27544576ull    // 64*8 int32 per-block bases

// async global->LDS, 16B per lane; LDS dest = wave-uniform base + lane*16
__device__ __forceinline__ void gload16(const void* g, void* l) {
    __builtin_amdgcn_global_load_lds(
        (const __attribute__((address_space(1))) unsigned int*)g,
        (__attribute__((address_space(3))) unsigned int*)l,
        16, 0, 0);
}

// per-block histogram -> bc[block][e]  (no global atomics)
__global__ void k_hist(const int* __restrict__ ids, const int* __restrict__ t2e,
                       int* __restrict__ bc) {
    __shared__ int h[EN];
    if (threadIdx.x < EN) h[threadIdx.x] = 0;
    __syncthreads();
    int t = blockIdx.x * 256 + threadIdx.x;
    int id = ids[t]; id = min(max(id, 0), VSZ - 1);
    atomicAdd(&h[t2e[id]], 1);
    __syncthreads();
    if (threadIdx.x < EN) bc[blockIdx.x * EN + threadIdx.x] = h[threadIdx.x];
}

// single block, 8 waves (one per expert): prefix over 64 blocks via shuffles
__global__ __launch_bounds__(512) void k_scan(const int* __restrict__ bc,
                                              int* __restrict__ bbase,
                                              int* __restrict__ meta) {
    int e = threadIdx.x >> 6;
    int b = threadIdx.x & 63;
    int c = bc[b * EN + e];
    int inc = c;
    #pragma unroll
    for (int s = 1; s < 64; s <<= 1) {
        int v = __shfl_up(inc, s, 64);
        if (b >= s) inc += v;
    }
    int exc = inc - c;
    __shared__ int tot[EN];
    __shared__ int goff[EN];
    if (b == 63) tot[e] = inc;
    __syncthreads();
    if (threadIdx.x == 0) {
        int off = 0, t1 = 0;
        meta[M_OFF] = 0; meta[M_TS1] = 0;
        #pragma unroll
        for (int i = 0; i < EN; ++i) {
            goff[i] = off;
            int cc = tot[i];
            off += cc; t1 += (cc + 31) >> 5;
            meta[M_OFF + i + 1] = off;
            meta[M_TS1 + i + 1] = t1;
        }
    }
    __syncthreads();
    bbase[b * EN + e] = goff[e] + exc;
}

// LDS cursors seeded from bbase -> zero global atomics
__global__ void k_assign(const int* __restrict__ ids, const int* __restrict__ t2e,
                         const int* __restrict__ bbase, int* __restrict__ perm) {
    __shared__ int cur[EN];
    if (threadIdx.x < EN) cur[threadIdx.x] = bbase[blockIdx.x * EN + threadIdx.x];
    __syncthreads();
    int t = blockIdx.x * 256 + threadIdx.x;
    int id = ids[t]; id = min(max(id, 0), VSZ - 1);
    int e = t2e[id];
    int slot = atomicAdd(&cur[e], 1);
    perm[slot] = t;
}

// ---------------------------------------------------------------------------
// k_pre: token-ordered activation quantization (blocks 0..4095, wave per token)
//        + weight repack into MFMA fragment layout (blocks 4096..5631).
// Fragment layout: elem(k,n) at ((k>>4)*N + n)*16 + (k&15)
// ---------------------------------------------------------------------------
__global__ __launch_bounds__(256) void k_pre(const float* __restrict__ hidden,
                                             const int* __restrict__ gq,
                                             const int* __restrict__ uq,
                                             const int* __restrict__ dq,
                                             signed char* __restrict__ xq,
                                             float* __restrict__ xs,
                                             signed char* __restrict__ pb1,
                                             signed char* __restrict__ pb2) {
    int b = blockIdx.x;
    if (b < 4096) {
        int w = threadIdx.x >> 6, lane = threadIdx.x & 63;
        int token = (b << 2) + w;
        const float* row = hidden + (size_t)token * HD;
        float v[16];
        #pragma unroll
        for (int j = 0; j < 4; ++j) {
            float4v f = *(const float4v*)(row + lane * 16 + j * 4);
            v[j*4+0] = f[0]; v[j*4+1] = f[1]; v[j*4+2] = f[2]; v[j*4+3] = f[3];
        }
        float mx = 0.0f;
        #pragma unroll
        for (int j = 0; j < 16; ++j) mx = fmaxf(mx, fabsf(v[j]));
        #pragma unroll
        for (int s = 1; s < 64; s <<= 1) mx = fmaxf(mx, __shfl_xor(mx, s, 64));
        float sc = fmaxf(mx / 127.0f, 1e-8f);
        if (lane == 0) xs[token] = sc;
        int4v pk;
        #pragma unroll
        for (int j = 0; j < 4; ++j) {
            int bb[4];
            #pragma unroll
            for (int u = 0; u < 4; ++u) {
                float t = rintf(v[j*4+u] / sc);           // round-half-even == jnp.round
                t = fminf(fmaxf(t, -128.0f), 127.0f);
                bb[u] = (int)t;
            }
            pk[j] = (bb[0] & 255) | ((bb[1] & 255) << 8) | ((bb[2] & 255) << 16) | (bb[3] << 24);
        }
        *(int4v*)(xq + (size_t)token * HD + lane * 16) = pk;
    } else {
        int idx = (b - 4096) * 256 + threadIdx.x;   // 0 .. 393215
        if (idx < 262144) {                          // gate|up fragments [8][64][512]
            int n = idx & 511, kc = (idx >> 9) & 63, e = idx >> 15;
            const int* src = (n < 256) ? gq + (((size_t)((e << 10) + (kc << 4)) << 8) + n)
                                       : uq + (((size_t)((e << 10) + (kc << 4)) << 8) + (n - 256));
            int4v pk;
            #pragma unroll
            for (int jj = 0; jj < 4; ++jj) {
                int b0 = src[(size_t)(jj * 4 + 0) << 8], b1 = src[(size_t)(jj * 4 + 1) << 8];
                int b2 = src[(size_t)(jj * 4 + 2) << 8], b3 = src[(size_t)(jj * 4 + 3) << 8];
                pk[jj] = (b0 & 255) | ((b1 & 255) << 8) | ((b2 & 255) << 16) | (b3 << 24);
            }
            *(int4v*)(pb1 + ((size_t)((((e << 6) + kc) << 9) + n) << 4)) = pk;
        } else {                                     // down fragments [8][16][1024]
            int j = idx - 262144;
            int n = j & 1023, kc = (j >> 10) & 15, e = j >> 14;
            const int* src = dq + (((size_t)((e << 8) + (kc << 4)) << 10) + n);
            int4v pk;
            #pragma unroll
            for (int jj = 0; jj < 4; ++jj) {
                int b0 = src[(size_t)(jj * 4 + 0) << 10], b1 = src[(size_t)(jj * 4 + 1) << 10];
                int b2 = src[(size_t)(jj * 4 + 2) << 10], b3 = src[(size_t)(jj * 4 + 3) << 10];
                pk[jj] = (b0 & 255) | ((b1 & 255) << 8) | ((b2 & 255) << 16) | (b3 << 24);
            }
            *(int4v*)(pb2 + ((size_t)((((e << 4) + kc) << 10) + n) << 4)) = pk;
        }
    }
}

// ---------------------------------------------------------------------------
// k_mlp: Mtile=32 fused MLP. 520 tiles -> 2 blocks/CU (LDS 72KB).
// Single barrier per K-step: barrier (drains prev stage) -> issue next stage
// -> ds_read+MFMA. Stage latency hides under compute of the previous tile.
// arena phase 1: [lA dbuf 4K][pmax 512B][rsc 128B][ptok 128B];
// epilogue overlays whole arena with the swizzled 32x256 int8 iq tile.
// XCD swizzle: tile = (b%8)*65 + b/8 so same-expert tiles share an XCD L2.
// ---------------------------------------------------------------------------
__global__ __launch_bounds__(256, 2) void k_mlp(const signed char* __restrict__ xq,
                                                const signed char* __restrict__ pb1,
                                                const signed char* __restrict__ pb2,
                                                const float* __restrict__ xs,
                                                const float* __restrict__ gsc,
                                                const float* __restrict__ usc,
                                                const float* __restrict__ dsc,
                                                const int* __restrict__ meta,
                                                const int* __restrict__ perm,
                                                float* __restrict__ out) {
    int b = (blockIdx.x & 7) * 65 + (blockIdx.x >> 3);   // XCD-contiguous tiles
    int e = -1, m0 = 0, gend = 0;
    #pragma unroll
    for (int i = 0; i < EN; ++i) {
        int s0 = meta[M_TS1 + i], s1 = meta[M_TS1 + i + 1];
        if (b >= s0 && b < s1) { e = i; m0 = meta[M_OFF + i] + ((b - s0) << 5); gend = meta[M_OFF + i + 1]; }
    }
    if (e < 0) return;
    const int w = threadIdx.x >> 6, lane = threadIdx.x & 63;
    const int q = lane >> 4, r = lane & 15;

    __shared__ __align__(16) signed char lB[2][32768];
    __shared__ __align__(16) signed char arena[8192];
    float* pmax = (float*)(arena + 4096);   // [4][32]
    float* rsc  = (float*)(arena + 4608);   // [32]
    int*   ptok = (int*)(arena + 4736);     // [32]

    if (threadIdx.x < 32) ptok[threadIdx.x] = perm[min(m0 + (int)threadIdx.x, T_TOK - 1)];
    __syncthreads();

    int tokr[2][4];
    #pragma unroll
    for (int mi = 0; mi < 2; ++mi)
        #pragma unroll
        for (int g = 0; g < 4; ++g)
            tokr[mi][g] = ptok[(mi << 4) + (q << 2) + g];

    const signed char* pbe1 = pb1 + (size_t)e * (64 * 512 * 16);
    const signed char* pbe2 = pb2 + (size_t)e * (16 * 1024 * 16);
    const int arow = (w << 4) + (lane >> 2);          // staging row (valid for w<2)
    const int acq  = (lane & 3) ^ ((lane >> 2) & 3);  // swizzled q-slot content
    const signed char* ga_base = xq + (size_t)ptok[arow & 31] * HD + (acq << 4);

    #define G1_STAGE(buf, kt)                                                          \
        {                                                                              \
            int kc0 = (kt) << 2;                                                       \
            _Pragma("unroll")                                                          \
            for (int j = 0; j < 8; ++j) {                                              \
                int n = ((j << 6) + lane) ^ ((w & 1) << 3);                            \
                gload16(pbe1 + (((size_t)(kc0 + w) * 512 + n) << 4),                   \
                        &lB[buf][((w << 3) + j) << 10]);                               \
            }                                                                          \
            if (w < 2) gload16(ga_base + ((kt) << 6), arena + ((buf) << 11) + (w << 10)); \
        }

    #define G2_STAGE(buf, st)                                                          \
        {                                                                              \
            int kc0 = ((st) & 3) << 2; int nhs = (st) >> 2;                            \
            _Pragma("unroll")                                                          \
            for (int j = 0; j < 8; ++j) {                                              \
                int n = ((j << 6) + lane) ^ ((w & 1) << 3);                            \
                gload16(pbe2 + (((size_t)(kc0 + w) * 1024 + (nhs << 9) + n) << 4),     \
                        &lB[buf][((w << 3) + j) << 10]);                               \
            }                                                                          \
        }

    int4v zero = {0, 0, 0, 0};
    int4v accg[2][4], accu[2][4];
    #pragma unroll
    for (int mi = 0; mi < 2; ++mi)
        #pragma unroll
        for (int i = 0; i < 4; ++i) { accg[mi][i] = zero; accu[mi][i] = zero; }

    // ---------------- phase 1: gate|up GEMM ----------------
    G1_STAGE(0, 0);
    for (int kt = 0; kt < 16; ++kt) {
        int cur = kt & 1;
        __syncthreads();                       // drains stage(cur); WAR guard
        if (kt < 15) G1_STAGE(cur ^ 1, kt + 1);
        int4v a[2];
        #pragma unroll
        for (int mi = 0; mi < 2; ++mi)
            a[mi] = *(const int4v*)&arena[(cur << 11) + ((((mi << 4) + r) << 6) + ((q ^ (r & 3)) << 4))];
        #pragma unroll
        for (int i = 0; i < 4; ++i) {
            int n = (w << 6) + (i << 4) + r;
            int sg = (q << 9) + (n ^ ((q & 1) << 3));
            int su = (q << 9) + ((n + 256) ^ ((q & 1) << 3));
            int4v bg = *(const int4v*)&lB[cur][sg << 4];
            int4v bu = *(const int4v*)&lB[cur][su << 4];
            #pragma unroll
            for (int mi = 0; mi < 2; ++mi) {
                accg[mi][i] = __builtin_amdgcn_mfma_i32_16x16x64_i8(a[mi], bg, accg[mi][i], 0, 0, 0);
                accu[mi][i] = __builtin_amdgcn_mfma_i32_16x16x64_i8(a[mi], bu, accu[mi][i], 0, 0, 0);
            }
        }
    }
    #undef G1_STAGE

    // prefetch first down-weight tile; HBM latency hides under the epilogue
    G2_STAGE(0, 0);

    // ---------------- epilogue: silu*up, row max, requant ----------------
    float gs[4], us[4];
    #pragma unroll
    for (int i = 0; i < 4; ++i) {
        int n = (w << 6) + (i << 4) + r;
        gs[i] = gsc[e * IE + n];
        us[i] = usc[e * IE + n];
    }
    float xsr[2][4];
    #pragma unroll
    for (int mi = 0; mi < 2; ++mi)
        #pragma unroll
        for (int g = 0; g < 4; ++g)
            xsr[mi][g] = xs[tokr[mi][g]];

    float inter[2][4][4];
    float pm[2][4];
    #pragma unroll
    for (int mi = 0; mi < 2; ++mi)
        #pragma unroll
        for (int g = 0; g < 4; ++g) {
            float mx = 0.0f;
            #pragma unroll
            for (int i = 0; i < 4; ++i) {
                float gv = (float)accg[mi][i][g] * xsr[mi][g] * gs[i];
                float uv = (float)accu[mi][i][g] * xsr[mi][g] * us[i];
                float sg = gv / (1.0f + expf(-gv));
                float vv = sg * uv;
                inter[mi][i][g] = vv;
                mx = fmaxf(mx, fabsf(vv));
            }
            #pragma unroll
            for (int s = 1; s < 16; s <<= 1) mx = fmaxf(mx, __shfl_xor(mx, s, 64));
            pm[mi][g] = mx;
        }

    __syncthreads();   // all GEMM1 lA reads done before pmax overwinds arena region
    if (r == 0) {
        #pragma unroll
        for (int mi = 0; mi < 2; ++mi)
            #pragma unroll
            for (int g = 0; g < 4; ++g)
                pmax[(w << 5) + (mi << 4) + (q << 2) + g] = pm[mi][g];
    }
    __syncthreads();
    if (threadIdx.x < 32) {
        int row = threadIdx.x;
        float mx = fmaxf(fmaxf(pmax[row], pmax[32 + row]), fmaxf(pmax[64 + row], pmax[96 + row]));
        rsc[row] = fmaxf(mx / 127.0f, 1e-8f);
    }
    __syncthreads();
    float rscr[2][4];
    #pragma unroll
    for (int mi = 0; mi < 2; ++mi)
        #pragma unroll
        for (int g = 0; g < 4; ++g)
            rscr[mi][g] = rsc[(mi << 4) + (q << 2) + g];
    __syncthreads();   // everyone done reading arena metadata before iq overlay

    // quantize inter -> swizzled LDS iq tile (overlays whole arena)
    // slot16(row, c) = c ^ (row & 3); byte = r
    #pragma unroll
    for (int mi = 0; mi < 2; ++mi)
        #pragma unroll
        for (int g = 0; g < 4; ++g) {
            int row = (mi << 4) + (q << 2) + g;
            float sc = rscr[mi][g];
            #pragma unroll
            for (int i = 0; i < 4; ++i) {
                float t = rintf(inter[mi][i][g] / sc);
                t = fminf(fmaxf(t, -128.0f), 127.0f);
                arena[(row << 8) + ((((w << 2) + i) ^ (row & 3)) << 4) + r] = (signed char)(int)t;
            }
        }

    // ---------------- phase 3: down GEMM, N in 2 halves ----------------
    int4v acc2[2][8];
    for (int st = 0; st < 8; ++st) {     // st = nh*4 + kt2
        int cur = st & 1;
        __syncthreads();                 // iq tile (st=0) + lB[cur] ready
        if (st < 7) G2_STAGE(cur ^ 1, st + 1);
        if ((st & 3) == 0) {
            #pragma unroll
            for (int mi = 0; mi < 2; ++mi)
                #pragma unroll
                for (int i = 0; i < 8; ++i) acc2[mi][i] = zero;
        }
        int4v a2[2];
        #pragma unroll
        for (int mi = 0; mi < 2; ++mi) {
            int row2 = (mi << 4) + r;
            a2[mi] = *(const int4v*)&arena[(row2 << 8) + (((((st & 3) << 2) + q) ^ (r & 3)) << 4)];
        }
        #pragma unroll
        for (int i = 0; i < 8; ++i) {
            int n = (w << 7) + (i << 4) + r;
            int sb = (q << 9) + (n ^ ((q & 1) << 3));
            int4v bb = *(const int4v*)&lB[cur][sb << 4];
            #pragma unroll
            for (int mi = 0; mi < 2; ++mi)
                acc2[mi][i] = __builtin_amdgcn_mfma_i32_16x16x64_i8(a2[mi], bb, acc2[mi][i], 0, 0, 0);
        }
        if ((st & 3) == 3) {
            int nhs = st >> 2;
            float ds[8];
            #pragma unroll
            for (int i = 0; i < 8; ++i)
                ds[i] = dsc[e * HD + (nhs << 9) + (w << 7) + (i << 4) + r];
            #pragma unroll
            for (int mi = 0; mi < 2; ++mi)
                #pragma unroll
                for (int g = 0; g < 4; ++g) {
                    int slot = m0 + (mi << 4) + (q << 2) + g;
                    if (slot < gend) {
                        size_t ob = (size_t)tokr[mi][g] * HD + (nhs << 9) + (w << 7) + r;
                        #pragma unroll
                        for (int i = 0; i < 8; ++i)
                            out[ob + (i << 4)] = (float)acc2[mi][i][g] * rscr[mi][g] * ds[i];
                    }
                }
        }
    }
    #undef G2_STAGE
}

extern "C" void kernel_launch(void* const* d_in, const int* in_sizes, int n_in,
                              void* d_out, int out_size, void* d_ws, size_t ws_size,
                              hipStream_t stream) {
    const float* hidden = (const float*)d_in[0];
    const int*   ids    = (const int*)d_in[1];
    const int*   gq     = (const int*)d_in[2];
    const float* gsc    = (const float*)d_in[3];
    const int*   uq     = (const int*)d_in[4];
    const float* usc    = (const float*)d_in[5];
    const int*   dq     = (const int*)d_in[6];
    const float* dsc    = (const float*)d_in[7];
    const int*   t2e    = (const int*)d_in[8];
    float* out = (float*)d_out;

    char* ws = (char*)d_ws;
    signed char* xq  = (signed char*)(ws + XQ_OFF);
    signed char* pb1 = (signed char*)(ws + PB1_OFF);
    signed char* pb2 = (signed char*)(ws + PB2_OFF);
    int*   perm = (int*)(ws + PERM_OFF);
    float* xs   = (float*)(ws + XS_OFF);
    int*   meta = (int*)(ws + META_OFF);
    int*   bc   = (int*)(ws + BC_OFF);
    int*   bbase= (int*)(ws + BB_OFF);

    k_hist<<<64, 256, 0, stream>>>(ids, t2e, bc);
    k_scan<<<1, 512, 0, stream>>>(bc, bbase, meta);
    k_assign<<<64, 256, 0, stream>>>(ids, t2e, bbase, perm);
    k_pre<<<5632, 256, 0, stream>>>(hidden, gq, uq, dq, xq, xs, pb1, pb2);
    k_mlp<<<520, 256, 0, stream>>>(xq, pb1, pb2, xs, gsc, usc, dsc, meta, perm, out);
}